// Round 19
// baseline (407.414 us; speedup 1.0000x reference)
//
#include <hip/hip_runtime.h>
#include <hip/hip_bf16.h>

typedef float f32x4 __attribute__((ext_vector_type(4)));
typedef unsigned int u32x4 __attribute__((ext_vector_type(4)));
typedef __bf16 bf16x8 __attribute__((ext_vector_type(8)));

#define NSP 4096
#define KTOT 2304

static __device__ __forceinline__ float bflo(unsigned u) {
  return __builtin_bit_cast(float, u << 16);
}
static __device__ __forceinline__ float bfhi(unsigned u) {
  return __builtin_bit_cast(float, u & 0xffff0000u);
}
static __device__ __forceinline__ unsigned short bfbits(float f) {
  return __builtin_bit_cast(unsigned short, (__bf16)f);
}
static __device__ __forceinline__ unsigned packbf2(float f0, float f1) {
  return (unsigned)bfbits(f0) | ((unsigned)bfbits(f1) << 16);
}
static __device__ __forceinline__ float bf16f(unsigned short h) {
  return __builtin_bit_cast(float, (unsigned)h << 16);
}

// async global->LDS DMA, 16B per lane (lds dest = wave-uniform base + lane*16)
static __device__ __forceinline__ void dma16(const unsigned short* g, unsigned short* l) {
  __builtin_amdgcn_global_load_lds(
      (const __attribute__((address_space(1))) unsigned int*)g,
      (__attribute__((address_space(3))) unsigned int*)l, 16, 0, 0);
}

// ---------- x (B,C,H,W) f32 -> XH (B,H,W,C) bf16 ----------
__global__ __launch_bounds__(256) void k_nhwc(const float* __restrict__ x,
                                              unsigned short* __restrict__ XH) {
  const int by = blockIdx.x;            // b*64 + y
  const int t = threadIdx.x;
  const int xw = t & 63;
  const int cq = t >> 6;                // 0..3
  const float* xp = x + (((by >> 6) * 256 * 64 + (by & 63)) * 64 + xw);
  unsigned short* oh = XH + (by * 64 + xw) * 256;
#pragma unroll
  for (int j8 = 0; j8 < 8; ++j8) {
    const int c0 = cq * 64 + j8 * 8;
    u32x4 vh;
#pragma unroll
    for (int d = 0; d < 4; ++d) {
      float f0 = xp[(c0 + 2 * d) * 4096];
      float f1 = xp[(c0 + 2 * d + 1) * 4096];
      vh[d] = packbf2(f0, f1);
    }
    *(u32x4*)(oh + c0) = vh;
  }
}

// ---------- weight prep (AWL pre-inverse-swizzled for DMA; AF fragment-order) ----------
__global__ void k_wprep_all(const float* __restrict__ wc, const float* __restrict__ wof,
                            unsigned short* __restrict__ AWL,
                            unsigned short* __restrict__ AF) {
  int idx = blockIdx.x * 256 + threadIdx.x;
  if (idx < 589824) {                     // 36*16384
    int ks = idx / 16384;
    int e = idx - ks * 16384;
    int row = e >> 6;                     // output channel o (0..255)
    int se = e & 63;                      // element within 128B LDS row
    int offb = (se * 2) ^ ((row & 7) << 4);  // unswizzled byte offset
    int col = ks * 64 + (offb >> 1);      // global K index
    int c = col & 255, tap = col >> 8;
    AWL[idx] = bfbits(wc[(row * 256 + c) * 9 + tap]);
  } else {
    int j = idx - 589824;
    if (j < 147456) {                     // 72*2048
      int skc = j >> 11;
      int r = j & 2047;
      int fi = r >> 9;                    // 0:hi m, 1:hi m+16, 2:lo m, 3:lo m+16
      int lane = (r >> 3) & 63;
      int e = r & 7;
      int ks = skc >> 1, kc = skc & 1;
      int tap = ks >> 2, q = ks & 3;
      int mr = lane & 15, ko = (lane >> 4) * 8;
      int m = (fi & 1) * 16 + mr;
      int gcol = tap * 256 + q * 64 + ko + kc * 32 + e;
      int c = gcol & 255;
      int t = gcol >> 8;
      float v = (m < 27) ? wof[(m * 256 + c) * 9 + t] : 0.f;
      unsigned short h = bfbits(v);
      AF[j] = (fi >> 1) ? bfbits(v - bf16f(h)) : h;
    }
  }
}

// ---------- offset conv: LDS-staged GEMM, dbuf + prefetch, coalesced A ----------
__global__ __launch_bounds__(256) void k_offc2(const unsigned short* __restrict__ AF,
                                               const unsigned short* __restrict__ XH,
                                               f32x4* __restrict__ W4,
                                               unsigned* __restrict__ C4) {
  __shared__ u32x4 ldsq[1024];   // 16 KB: 2 x 8 KB B-tile dbuf; reused for 8 KB acc
  unsigned char* ldsbase = (unsigned char*)ldsq;
  float* lds32 = (float*)ldsq;

  const int tid = threadIdx.x;
  const int bid = blockIdx.x;            // y(64) x b(8)
  const int b = bid & 7;                 // XCD swizzle: one batch per XCD
  const int y = bid >> 3;
  const int l = tid & 63;
  const int w = tid >> 6;

  const unsigned short* xb = XH + b * (64 * 64 * 256);
  const int sp = tid >> 2;
  const int qtr = tid & 3;
  const unsigned swb = (unsigned)(sp & 7) << 4;
  const int col = w * 16 + (l & 15);
  const unsigned swc = (unsigned)(col & 7) << 4;

  f32x4 acc0 = (f32x4){0.f, 0.f, 0.f, 0.f};
  f32x4 acc1 = (f32x4){0.f, 0.f, 0.f, 0.f};
  u32x4 v0, v1;

  // prologue: stage step 0 into buffer 0
  {
    const int yy = y - 1;
    const int xx = sp - 1;
    const bool valid = ((unsigned)yy < 64u) & ((unsigned)xx < 64u);
    const int yyc = min(max(yy, 0), 63), xxc = min(max(xx, 0), 63);
    const unsigned short* src = xb + ((yyc * 64 + xxc) * 256 + qtr * 16);
    u32x4 z = (u32x4){0u, 0u, 0u, 0u};
    v0 = valid ? *(const u32x4*)src : z;
    v1 = valid ? *(const u32x4*)(src + 8) : z;
    *(u32x4*)(ldsbase + (unsigned)sp * 128u + (((unsigned)(qtr * 32)) ^ swb)) = v0;
    *(u32x4*)(ldsbase + (unsigned)sp * 128u + (((unsigned)(qtr * 32 + 16)) ^ swb)) = v1;
  }

  for (int ks = 0; ks < 36; ++ks) {
    unsigned char* ldsB = ldsbase + (ks & 1) * 8192;
    unsigned char* ldsBn = ldsbase + ((ks & 1) ^ 1) * 8192;
    const bool pf = (ks + 1 < 36);

    // prefetch next stage BEFORE the barrier (stays in flight across it)
    if (pf) {
      int tap = (ks + 1) >> 2, q = (ks + 1) & 3;
      int yy = y + tap / 3 - 1, xx = sp + tap % 3 - 1;
      bool valid = ((unsigned)yy < 64u) & ((unsigned)xx < 64u);
      int yyc = min(max(yy, 0), 63), xxc = min(max(xx, 0), 63);
      const unsigned short* src = xb + ((yyc * 64 + xxc) * 256 + q * 64 + qtr * 16);
      u32x4 z = (u32x4){0u, 0u, 0u, 0u};
      v0 = valid ? *(const u32x4*)src : z;
      v1 = valid ? *(const u32x4*)(src + 8) : z;
    }

    // LDS-only barrier: publish buf[cur] writes, retire buf[cur^1] reads
    asm volatile("s_waitcnt lgkmcnt(0)" ::: "memory");
    __builtin_amdgcn_s_barrier();

    const unsigned short* af = AF + ks * 4096;
#pragma unroll
    for (int kc = 0; kc < 2; ++kc) {
      bf16x8 ah0 = *(const bf16x8*)(af + kc * 2048 + l * 8);
      bf16x8 ah1 = *(const bf16x8*)(af + kc * 2048 + 512 + l * 8);
      bf16x8 al0 = *(const bf16x8*)(af + kc * 2048 + 1024 + l * 8);
      bf16x8 al1 = *(const bf16x8*)(af + kc * 2048 + 1536 + l * 8);
      bf16x8 bh = *(const bf16x8*)(ldsB + (unsigned)col * 128u +
                                   (((unsigned)(kc * 64 + (l >> 4) * 16)) ^ swc));
      acc0 = __builtin_amdgcn_mfma_f32_16x16x32_bf16(ah0, bh, acc0, 0, 0, 0);
      acc1 = __builtin_amdgcn_mfma_f32_16x16x32_bf16(ah1, bh, acc1, 0, 0, 0);
      acc0 = __builtin_amdgcn_mfma_f32_16x16x32_bf16(al0, bh, acc0, 0, 0, 0);
      acc1 = __builtin_amdgcn_mfma_f32_16x16x32_bf16(al1, bh, acc1, 0, 0, 0);
    }

    // write next stage into the other buffer (read side untouched)
    if (pf) {
      *(u32x4*)(ldsBn + (unsigned)sp * 128u + (((unsigned)(qtr * 32)) ^ swb)) = v0;
      *(u32x4*)(ldsBn + (unsigned)sp * 128u + (((unsigned)(qtr * 32 + 16)) ^ swb)) = v1;
    }
  }

  // stage acc -> lds32 [32 m][64 px]  (D layout: col=lane&15, row=(l>>4)*4+reg)
  __syncthreads();
#pragma unroll
  for (int mf = 0; mf < 2; ++mf) {
    f32x4 a = mf ? acc1 : acc0;
#pragma unroll
    for (int r = 0; r < 4; ++r) {
      int m = mf * 16 + (l >> 4) * 4 + r;
      int px = w * 16 + (l & 15);
      lds32[m * 64 + px] = a[r];
    }
  }
  __syncthreads();

  // fused xform: per (k, px) compute bilinear weights + packed corner indices
#pragma unroll
  for (int it = 0; it < 3; ++it) {
    int idx = tid + it * 256;
    if (idx < 9 * 64) {
      int k = idx >> 6, px = idx & 63;
      float oy = lds32[k * 64 + px];
      float ox = lds32[(9 + k) * 64 + px];
      float lg = lds32[(18 + k) * 64 + px];
      int s = y * 64 + px;
      float py = oy + (float)y - 1.f + (float)(k / 3);
      float pxf = ox + (float)px - 1.f + (float)(k % 3);
      float mk = 1.f / (1.f + __expf(-lg));

      float y0f = floorf(py), x0f = floorf(pxf);
      float ly = py - y0f, lx = pxf - x0f;
      int y0 = (int)y0f, x0 = (int)x0f;
      int y1 = y0 + 1, x1 = x0 + 1;
      float omy = 1.f - ly, omx = 1.f - lx;
      bool y0v = (unsigned)y0 < 64u, y1v = (unsigned)y1 < 64u;
      bool x0v = (unsigned)x0 < 64u, x1v = (unsigned)x1 < 64u;
      f32x4 wv;
      wv[0] = (y0v && x0v) ? omy * omx * mk : 0.f;
      wv[1] = (y0v && x1v) ? omy * lx * mk : 0.f;
      wv[2] = (y1v && x0v) ? ly * omx * mk : 0.f;
      wv[3] = (y1v && x1v) ? ly * lx * mk : 0.f;
      int y0c = min(max(y0, 0), 63), y1c = min(max(y1, 0), 63);
      int x0c = min(max(x0, 0), 63), x1c = min(max(x1, 0), 63);
      unsigned p00 = (unsigned)(y0c * 64 + x0c);
      unsigned p11 = (unsigned)(y1c * 64 + x1c);
      int ci = (b * 9 + k) * NSP + s;
      W4[ci] = wv;
      C4[ci] = p00 | (p11 << 16);
    }
  }
}

// ---------- fused sampling + implicit GEMM (K-split x2, 2 blocks/CU) ----------
struct Bld16 {
  u32x4 g00a, g00b, g01a, g01b, g10a, g10b, g11a, g11b;
  f32x4 wv;
};

static __device__ __forceinline__ void loadMeta(const f32x4* __restrict__ W4,
                                                const unsigned* __restrict__ C4,
                                                int b, int k, int s,
                                                f32x4& wv, unsigned& c4) {
  int ci = (b * 9 + k) * NSP + s;
  wv = W4[ci];
  c4 = C4[ci];
}

static __device__ __forceinline__ void loadCorners(const unsigned short* __restrict__ xb,
                                                   f32x4 wv, unsigned c4, int c0, int bc,
                                                   Bld16& r) {
  r.wv = wv;
  unsigned p00 = c4 & 0xffffu, p11 = c4 >> 16;
  unsigned p01 = (p00 & ~63u) | (p11 & 63u);
  unsigned p10 = (p11 & ~63u) | (p00 & 63u);
  const unsigned short* base = xb + (c0 + bc);
  const unsigned short* q00 = base + (p00 << 8);
  const unsigned short* q01 = base + (p01 << 8);
  const unsigned short* q10 = base + (p10 << 8);
  const unsigned short* q11 = base + (p11 << 8);
  r.g00a = *(const u32x4*)q00;
  r.g00b = *(const u32x4*)(q00 + 8);
  r.g01a = *(const u32x4*)q01;
  r.g01b = *(const u32x4*)(q01 + 8);
  r.g10a = *(const u32x4*)q10;
  r.g10b = *(const u32x4*)(q10 + 8);
  r.g11a = *(const u32x4*)q11;
  r.g11b = *(const u32x4*)(q11 + 8);
}

static __device__ __forceinline__ void blendB16(const Bld16& r, u32x4& o0, u32x4& o1) {
#pragma unroll
  for (int d = 0; d < 4; ++d) {
    float a0 = r.wv[0] * bflo(r.g00a[d]) + r.wv[1] * bflo(r.g01a[d]) +
               r.wv[2] * bflo(r.g10a[d]) + r.wv[3] * bflo(r.g11a[d]);
    float a1 = r.wv[0] * bfhi(r.g00a[d]) + r.wv[1] * bfhi(r.g01a[d]) +
               r.wv[2] * bfhi(r.g10a[d]) + r.wv[3] * bfhi(r.g11a[d]);
    o0[d] = packbf2(a0, a1);
    float b0 = r.wv[0] * bflo(r.g00b[d]) + r.wv[1] * bflo(r.g01b[d]) +
               r.wv[2] * bflo(r.g10b[d]) + r.wv[3] * bflo(r.g11b[d]);
    float b1 = r.wv[0] * bfhi(r.g00b[d]) + r.wv[1] * bfhi(r.g01b[d]) +
               r.wv[2] * bfhi(r.g10b[d]) + r.wv[3] * bfhi(r.g11b[d]);
    o1[d] = packbf2(b0, b1);
  }
}

__global__ __launch_bounds__(512, 4) void k_gemm(const unsigned short* __restrict__ AWL,
                                                 const unsigned short* __restrict__ XH,
                                                 const f32x4* __restrict__ W4,
                                                 const unsigned* __restrict__ C4v,
                                                 float* __restrict__ out) {
  // 80 KB LDS -> 2 blocks/CU: A dbuf 2x32 KB (DMA) + SINGLE B buffer 16 KB
  __shared__ u32x4 lds2[5120];
  unsigned char* ldsbase = (unsigned char*)lds2;
  unsigned char* ldsB = ldsbase + 65536;

  const int tid = threadIdx.x;
  const int bid = blockIdx.x;           // b(8) x s(32) x kh(2)
  const int b = bid & 7;                // XCD swizzle: one batch per XCD
  const int s0 = ((bid >> 3) & 31) * 128;
  const int kb = (bid >> 8) * 18;       // K-half base step

  const int l = tid & 63;
  const int w = tid >> 6;
  const int wm = (w >> 1) * 64;  // 4 M-waves
  const int wn = (w & 1) * 64;   // 2 N-waves

  const int bn = tid >> 2;
  const int bc = (tid & 3) * 16;
  const int s = s0 + bn;
  const unsigned swb = (unsigned)(bn & 7) << 4;
  const unsigned short* xb = XH + b * (64 * 64 * 256);

  f32x4 acc[4][4];
#pragma unroll
  for (int i = 0; i < 4; ++i)
#pragma unroll
    for (int j = 0; j < 4; ++j) acc[i][j] = (f32x4){0.f, 0.f, 0.f, 0.f};

  // 2-deep pipeline register sets (named, statically indexed — rule #20)
  f32x4 mwvA, mwvB;
  unsigned mc4A, mc4B;
  Bld16 bldA, bldB;

  // ---- prologue (global step G = kb + local ks) ----
  loadMeta(W4, C4v, b, kb >> 2, s, mwvA, mc4A);         // meta(G0)
  loadMeta(W4, C4v, b, (kb + 1) >> 2, s, mwvB, mc4B);   // meta(G0+1)
  {
    // DMA A(G0) into A buffer 0 (linear deposit; AWL is pre-inverse-swizzled)
    const unsigned short* g0 = AWL + kb * 16384 + (w * 4) * 512 + l * 8;
#pragma unroll
    for (int k = 0; k < 4; ++k)
      dma16(g0 + k * 512, (unsigned short*)(ldsbase + (unsigned)(w * 4 + k) * 1024u));
  }
  loadCorners(xb, mwvA, mc4A, (kb & 3) << 6, bc, bldA);  // corners(G0)
  loadMeta(W4, C4v, b, (kb + 2) >> 2, s, mwvA, mc4A);    // meta(G0+2)
  {
    u32x4 o0, o1;
    blendB16(bldA, o0, o1);
    const unsigned bbase = (unsigned)bn * 128u;
    *(u32x4*)(ldsB + bbase + (((unsigned)(bc * 2)) ^ swb)) = o0;
    *(u32x4*)(ldsB + bbase + (((unsigned)(bc * 2 + 16)) ^ swb)) = o1;
  }
  loadCorners(xb, mwvB, mc4B, ((kb + 1) & 3) << 6, bc, bldB);  // corners(G0+1)

  auto mfma_half = [&](unsigned char* ldsA, int H) {
    bf16x8 af[4], bfr[4];
    const unsigned co = (unsigned)(H * 64 + ((l >> 4) * 16));
#pragma unroll
    for (int i = 0; i < 4; ++i) {
      int row = wm + i * 16 + (l & 15);
      af[i] = *(const bf16x8*)(ldsA + (unsigned)row * 128u +
                               (co ^ ((unsigned)(row & 7) << 4)));
    }
#pragma unroll
    for (int j = 0; j < 4; ++j) {
      int col = wn + j * 16 + (l & 15);
      bfr[j] = *(const bf16x8*)(ldsB + (unsigned)col * 128u +
                                (co ^ ((unsigned)(col & 7) << 4)));
    }
#pragma unroll
    for (int i = 0; i < 4; ++i)
#pragma unroll
      for (int j = 0; j < 4; ++j)
        acc[i][j] = __builtin_amdgcn_mfma_f32_16x16x32_bf16(af[i], bfr[j],
                                                            acc[i][j], 0, 0, 0);
  };

  // step KS (local 0..17): two-barrier discipline for the single B buffer:
  //   barrier1 (__syncthreads): DMA A(KS) landed + B(KS) writes visible
  //   MFMA reads  ->  barrier2 (lgkmcnt-only)  ->  blend-writes B(KS+1)
  auto gstep = [&](int KS, Bld16& bldI, f32x4& mwvI, unsigned& mc4I,
                   f32x4& mwvO, unsigned& mc4O, Bld16& bldU) {
    const int G = kb + KS;
    unsigned char* ldsA = ldsbase + (KS & 1) * 32768;
    unsigned char* ldsAn = ldsbase + ((KS & 1) ^ 1) * 32768;

    __syncthreads();  // barrier1: vmcnt drain -> DMA A(KS) complete; B(KS) published

    // issue DMA A(KS+1) — targets the A buffer whose reads ended before barrier1
    if (KS + 1 < 18) {
      const unsigned short* g0 = AWL + (G + 1) * 16384 + (w * 4) * 512 + l * 8;
#pragma unroll
      for (int k = 0; k < 4; ++k)
        dma16(g0 + k * 512, (unsigned short*)(ldsAn + (unsigned)(w * 4 + k) * 1024u));
    }

    __builtin_amdgcn_s_setprio(1);
    mfma_half(ldsA, 0);
    __builtin_amdgcn_s_setprio(0);

    // issue corners(G+2) — addresses from meta loaded a full step ago
    if (KS + 2 < 18)
      loadCorners(xb, mwvI, mc4I, ((G + 2) & 3) << 6, bc, bldI);
    // issue meta(G+3) into the freed opposite meta set
    if (KS + 3 < 18)
      loadMeta(W4, C4v, b, (G + 3) >> 2, s, mwvO, mc4O);

    __builtin_amdgcn_s_setprio(1);
    mfma_half(ldsA, 1);
    __builtin_amdgcn_s_setprio(0);

    // barrier2: all waves' B reads retired (LDS-only; corner loads stay in flight)
    asm volatile("s_waitcnt lgkmcnt(0)" ::: "memory");
    __builtin_amdgcn_s_barrier();

    // blend + write B(KS+1) into the single B buffer
    if (KS + 1 < 18) {
      u32x4 o0, o1;
      blendB16(bldU, o0, o1);
      const unsigned bbase = (unsigned)bn * 128u;
      *(u32x4*)(ldsB + bbase + (((unsigned)(bc * 2)) ^ swb)) = o0;
      *(u32x4*)(ldsB + bbase + (((unsigned)(bc * 2 + 16)) ^ swb)) = o1;
    }
  };

  for (int ks2 = 0; ks2 < 18; ks2 += 2) {
    gstep(ks2, bldA, mwvA, mc4A, mwvB, mc4B, bldB);
    gstep(ks2 + 1, bldB, mwvB, mc4B, mwvA, mc4A, bldA);
  }

  // epilogue: atomic-accumulate K-half partial (out zeroed by memsetAsync)
  const int cn2 = l & 15;
  const int r0 = (l >> 4) * 4;
#pragma unroll
  for (int i = 0; i < 4; ++i) {
#pragma unroll
    for (int j = 0; j < 4; ++j) {
      int sc = s0 + wn + j * 16 + cn2;
#pragma unroll
      for (int r = 0; r < 4; ++r) {
        int o = wm + i * 16 + r0 + r;
        atomicAdd(&out[((b * 256 + o) << 12) + sc], acc[i][j][r]);
      }
    }
  }
}

extern "C" void kernel_launch(void* const* d_in, const int* in_sizes, int n_in,
                              void* d_out, int out_size, void* d_ws, size_t ws_size,
                              hipStream_t stream) {
  const float* x = (const float*)d_in[0];
  const float* wof = (const float*)d_in[1];
  const float* wc = (const float*)d_in[2];
  float* out = (float*)d_out;
  char* ws = (char*)d_ws;

  // ws layout (total 24.2 MB)
  unsigned short* XH = (unsigned short*)(ws);              // 16,777,216 B
  unsigned short* AWL = (unsigned short*)(ws + 16777216);  //  1,179,648 B
  unsigned short* AF = (unsigned short*)(ws + 17956864);   //    294,912 B
  f32x4* W4 = (f32x4*)(ws + 18251776);                     //  4,718,592 B
  unsigned* C4 = (unsigned*)(ws + 22970368);               //  1,179,648 B (end 24,150,016)

  hipMemsetAsync(d_out, 0, (size_t)out_size * 4, stream);  // atomic accumulation target
  k_nhwc<<<512, 256, 0, stream>>>(x, XH);
  k_wprep_all<<<2880, 256, 0, stream>>>(wc, wof, AWL, AF);
  k_offc2<<<512, 256, 0, stream>>>(AF, XH, W4, C4);
  k_gemm<<<512, 512, 0, stream>>>(AWL, XH, W4, C4, out);
}

// Round 20
// 140.236 us; speedup vs baseline: 2.9052x; 2.9052x over previous
//
#include <hip/hip_runtime.h>
#include <hip/hip_bf16.h>

typedef float f32x4 __attribute__((ext_vector_type(4)));
typedef unsigned int u32x4 __attribute__((ext_vector_type(4)));
typedef __bf16 bf16x8 __attribute__((ext_vector_type(8)));

#define NSP 4096
#define KTOT 2304

static __device__ __forceinline__ float bflo(unsigned u) {
  return __builtin_bit_cast(float, u << 16);
}
static __device__ __forceinline__ float bfhi(unsigned u) {
  return __builtin_bit_cast(float, u & 0xffff0000u);
}
static __device__ __forceinline__ unsigned short bfbits(float f) {
  return __builtin_bit_cast(unsigned short, (__bf16)f);
}
static __device__ __forceinline__ unsigned packbf2(float f0, float f1) {
  return (unsigned)bfbits(f0) | ((unsigned)bfbits(f1) << 16);
}
static __device__ __forceinline__ float bf16f(unsigned short h) {
  return __builtin_bit_cast(float, (unsigned)h << 16);
}

// async global->LDS DMA, 16B per lane (lds dest = wave-uniform base + lane*16)
static __device__ __forceinline__ void dma16(const unsigned short* g, unsigned short* l) {
  __builtin_amdgcn_global_load_lds(
      (const __attribute__((address_space(1))) unsigned int*)g,
      (__attribute__((address_space(3))) unsigned int*)l, 16, 0, 0);
}

// ---------- x (B,C,H,W) f32 -> XH (B,H,W,C) bf16 ----------
__global__ __launch_bounds__(256) void k_nhwc(const float* __restrict__ x,
                                              unsigned short* __restrict__ XH) {
  const int by = blockIdx.x;            // b*64 + y
  const int t = threadIdx.x;
  const int xw = t & 63;
  const int cq = t >> 6;                // 0..3
  const float* xp = x + (((by >> 6) * 256 * 64 + (by & 63)) * 64 + xw);
  unsigned short* oh = XH + (by * 64 + xw) * 256;
#pragma unroll
  for (int j8 = 0; j8 < 8; ++j8) {
    const int c0 = cq * 64 + j8 * 8;
    u32x4 vh;
#pragma unroll
    for (int d = 0; d < 4; ++d) {
      float f0 = xp[(c0 + 2 * d) * 4096];
      float f1 = xp[(c0 + 2 * d + 1) * 4096];
      vh[d] = packbf2(f0, f1);
    }
    *(u32x4*)(oh + c0) = vh;
  }
}

// ---------- weight prep (AWL pre-inverse-swizzled for DMA; AF fragment-order) ----------
__global__ void k_wprep_all(const float* __restrict__ wc, const float* __restrict__ wof,
                            unsigned short* __restrict__ AWL,
                            unsigned short* __restrict__ AF) {
  int idx = blockIdx.x * 256 + threadIdx.x;
  if (idx < 589824) {                     // 36*16384
    int ks = idx / 16384;
    int e = idx - ks * 16384;
    int row = e >> 6;                     // output channel o (0..255)
    int se = e & 63;                      // element within 128B LDS row
    int offb = (se * 2) ^ ((row & 7) << 4);  // unswizzled byte offset
    int col = ks * 64 + (offb >> 1);      // global K index
    int c = col & 255, tap = col >> 8;
    AWL[idx] = bfbits(wc[(row * 256 + c) * 9 + tap]);
  } else {
    int j = idx - 589824;
    if (j < 147456) {                     // 72*2048
      int skc = j >> 11;
      int r = j & 2047;
      int fi = r >> 9;                    // 0:hi m, 1:hi m+16, 2:lo m, 3:lo m+16
      int lane = (r >> 3) & 63;
      int e = r & 7;
      int ks = skc >> 1, kc = skc & 1;
      int tap = ks >> 2, q = ks & 3;
      int mr = lane & 15, ko = (lane >> 4) * 8;
      int m = (fi & 1) * 16 + mr;
      int gcol = tap * 256 + q * 64 + ko + kc * 32 + e;
      int c = gcol & 255;
      int t = gcol >> 8;
      float v = (m < 27) ? wof[(m * 256 + c) * 9 + t] : 0.f;
      unsigned short h = bfbits(v);
      AF[j] = (fi >> 1) ? bfbits(v - bf16f(h)) : h;
    }
  }
}

// ---------- offset conv: LDS-staged GEMM, dbuf + prefetch, coalesced A ----------
__global__ __launch_bounds__(256) void k_offc2(const unsigned short* __restrict__ AF,
                                               const unsigned short* __restrict__ XH,
                                               f32x4* __restrict__ W4,
                                               unsigned* __restrict__ C4) {
  __shared__ u32x4 ldsq[1024];   // 16 KB: 2 x 8 KB B-tile dbuf; reused for 8 KB acc
  unsigned char* ldsbase = (unsigned char*)ldsq;
  float* lds32 = (float*)ldsq;

  const int tid = threadIdx.x;
  const int bid = blockIdx.x;            // y(64) x b(8)
  const int b = bid & 7;                 // XCD swizzle: one batch per XCD
  const int y = bid >> 3;
  const int l = tid & 63;
  const int w = tid >> 6;

  const unsigned short* xb = XH + b * (64 * 64 * 256);
  const int sp = tid >> 2;
  const int qtr = tid & 3;
  const unsigned swb = (unsigned)(sp & 7) << 4;
  const int col = w * 16 + (l & 15);
  const unsigned swc = (unsigned)(col & 7) << 4;

  f32x4 acc0 = (f32x4){0.f, 0.f, 0.f, 0.f};
  f32x4 acc1 = (f32x4){0.f, 0.f, 0.f, 0.f};
  u32x4 v0, v1;

  // prologue: stage step 0 into buffer 0
  {
    const int yy = y - 1;
    const int xx = sp - 1;
    const bool valid = ((unsigned)yy < 64u) & ((unsigned)xx < 64u);
    const int yyc = min(max(yy, 0), 63), xxc = min(max(xx, 0), 63);
    const unsigned short* src = xb + ((yyc * 64 + xxc) * 256 + qtr * 16);
    u32x4 z = (u32x4){0u, 0u, 0u, 0u};
    v0 = valid ? *(const u32x4*)src : z;
    v1 = valid ? *(const u32x4*)(src + 8) : z;
    *(u32x4*)(ldsbase + (unsigned)sp * 128u + (((unsigned)(qtr * 32)) ^ swb)) = v0;
    *(u32x4*)(ldsbase + (unsigned)sp * 128u + (((unsigned)(qtr * 32 + 16)) ^ swb)) = v1;
  }

  for (int ks = 0; ks < 36; ++ks) {
    unsigned char* ldsB = ldsbase + (ks & 1) * 8192;
    unsigned char* ldsBn = ldsbase + ((ks & 1) ^ 1) * 8192;
    const bool pf = (ks + 1 < 36);

    // prefetch next stage BEFORE the barrier (stays in flight across it)
    if (pf) {
      int tap = (ks + 1) >> 2, q = (ks + 1) & 3;
      int yy = y + tap / 3 - 1, xx = sp + tap % 3 - 1;
      bool valid = ((unsigned)yy < 64u) & ((unsigned)xx < 64u);
      int yyc = min(max(yy, 0), 63), xxc = min(max(xx, 0), 63);
      const unsigned short* src = xb + ((yyc * 64 + xxc) * 256 + q * 64 + qtr * 16);
      u32x4 z = (u32x4){0u, 0u, 0u, 0u};
      v0 = valid ? *(const u32x4*)src : z;
      v1 = valid ? *(const u32x4*)(src + 8) : z;
    }

    // LDS-only barrier: publish buf[cur] writes, retire buf[cur^1] reads
    asm volatile("s_waitcnt lgkmcnt(0)" ::: "memory");
    __builtin_amdgcn_s_barrier();

    const unsigned short* af = AF + ks * 4096;
#pragma unroll
    for (int kc = 0; kc < 2; ++kc) {
      bf16x8 ah0 = *(const bf16x8*)(af + kc * 2048 + l * 8);
      bf16x8 ah1 = *(const bf16x8*)(af + kc * 2048 + 512 + l * 8);
      bf16x8 al0 = *(const bf16x8*)(af + kc * 2048 + 1024 + l * 8);
      bf16x8 al1 = *(const bf16x8*)(af + kc * 2048 + 1536 + l * 8);
      bf16x8 bh = *(const bf16x8*)(ldsB + (unsigned)col * 128u +
                                   (((unsigned)(kc * 64 + (l >> 4) * 16)) ^ swc));
      acc0 = __builtin_amdgcn_mfma_f32_16x16x32_bf16(ah0, bh, acc0, 0, 0, 0);
      acc1 = __builtin_amdgcn_mfma_f32_16x16x32_bf16(ah1, bh, acc1, 0, 0, 0);
      acc0 = __builtin_amdgcn_mfma_f32_16x16x32_bf16(al0, bh, acc0, 0, 0, 0);
      acc1 = __builtin_amdgcn_mfma_f32_16x16x32_bf16(al1, bh, acc1, 0, 0, 0);
    }

    // write next stage into the other buffer (read side untouched)
    if (pf) {
      *(u32x4*)(ldsBn + (unsigned)sp * 128u + (((unsigned)(qtr * 32)) ^ swb)) = v0;
      *(u32x4*)(ldsBn + (unsigned)sp * 128u + (((unsigned)(qtr * 32 + 16)) ^ swb)) = v1;
    }
  }

  // stage acc -> lds32 [32 m][64 px]  (D layout: col=lane&15, row=(l>>4)*4+reg)
  __syncthreads();
#pragma unroll
  for (int mf = 0; mf < 2; ++mf) {
    f32x4 a = mf ? acc1 : acc0;
#pragma unroll
    for (int r = 0; r < 4; ++r) {
      int m = mf * 16 + (l >> 4) * 4 + r;
      int px = w * 16 + (l & 15);
      lds32[m * 64 + px] = a[r];
    }
  }
  __syncthreads();

  // fused xform: per (k, px) compute bilinear weights + packed corner indices
#pragma unroll
  for (int it = 0; it < 3; ++it) {
    int idx = tid + it * 256;
    if (idx < 9 * 64) {
      int k = idx >> 6, px = idx & 63;
      float oy = lds32[k * 64 + px];
      float ox = lds32[(9 + k) * 64 + px];
      float lg = lds32[(18 + k) * 64 + px];
      int s = y * 64 + px;
      float py = oy + (float)y - 1.f + (float)(k / 3);
      float pxf = ox + (float)px - 1.f + (float)(k % 3);
      float mk = 1.f / (1.f + __expf(-lg));

      float y0f = floorf(py), x0f = floorf(pxf);
      float ly = py - y0f, lx = pxf - x0f;
      int y0 = (int)y0f, x0 = (int)x0f;
      int y1 = y0 + 1, x1 = x0 + 1;
      float omy = 1.f - ly, omx = 1.f - lx;
      bool y0v = (unsigned)y0 < 64u, y1v = (unsigned)y1 < 64u;
      bool x0v = (unsigned)x0 < 64u, x1v = (unsigned)x1 < 64u;
      f32x4 wv;
      wv[0] = (y0v && x0v) ? omy * omx * mk : 0.f;
      wv[1] = (y0v && x1v) ? omy * lx * mk : 0.f;
      wv[2] = (y1v && x0v) ? ly * omx * mk : 0.f;
      wv[3] = (y1v && x1v) ? ly * lx * mk : 0.f;
      int y0c = min(max(y0, 0), 63), y1c = min(max(y1, 0), 63);
      int x0c = min(max(x0, 0), 63), x1c = min(max(x1, 0), 63);
      unsigned p00 = (unsigned)(y0c * 64 + x0c);
      unsigned p11 = (unsigned)(y1c * 64 + x1c);
      int ci = (b * 9 + k) * NSP + s;
      W4[ci] = wv;
      C4[ci] = p00 | (p11 << 16);
    }
  }
}

// ---------- fused sampling + implicit GEMM: producer/consumer wave split ----------
// 12 waves: tid<512 = 8 consumer waves (A-DMA + MFMA), tid>=512 = 4 producer
// waves (meta -> corner gather -> blend -> B write). One __syncthreads per
// K-step; A and B both double-buffered; every cross-wave RAW/WAR pair is
// separated by >=1 full-drain barrier.
__global__ __launch_bounds__(768, 3) void k_gemm(const unsigned short* __restrict__ AWL,
                                                 const unsigned short* __restrict__ XH,
                                                 const f32x4* __restrict__ W4,
                                                 const unsigned* __restrict__ C4v,
                                                 float* __restrict__ out) {
  // LDS 96 KB: A dbuf 2x32 KB (DMA, pre-swizzled) at 0; B dbuf 2x16 KB at 64K
  __shared__ u32x4 lds2[6144];
  unsigned char* ldsbase = (unsigned char*)lds2;
  unsigned char* ldsBbase = ldsbase + 65536;

  const int tid = threadIdx.x;
  const int bid = blockIdx.x;
  const int b = bid & 7;          // XCD swizzle: one batch per XCD
  const int s0 = (bid >> 3) * 128;
  const unsigned short* xb = XH + b * (64 * 64 * 256);

  const bool isProd = tid >= 512;

  // ---- consumer identity ----
  const int l = tid & 63;
  const int w = tid >> 6;         // consumers: 0..7
  const int wm = (w >> 1) * 64;
  const int wn = (w & 1) * 64;

  // ---- producer identity: 256 threads, pixel px (0..127), 32-ch half ----
  const int pt = tid - 512;
  const int px = pt >> 1;
  const int chb = (pt & 1) * 32;
  const int ps = s0 + px;
  const unsigned swb = (unsigned)(px & 7) << 4;

  f32x4 acc[4][4];
#pragma unroll
  for (int i = 0; i < 4; ++i)
#pragma unroll
    for (int j = 0; j < 4; ++j) acc[i][j] = (f32x4){0.f, 0.f, 0.f, 0.f};

  // producer registers: single corner set + meta
  u32x4 c00[4], c01[4], c10[4], c11[4];
  f32x4 mwv;
  unsigned mc4 = 0u;

  // ---- prologue ----
  if (!isProd) {
    // DMA A(0) into A buffer 0 (linear deposit; AWL pre-inverse-swizzled)
    const unsigned short* g0 = AWL + (w * 4) * 512 + l * 8;
#pragma unroll
    for (int k = 0; k < 4; ++k)
      dma16(g0 + k * 512, (unsigned short*)(ldsbase + (unsigned)(w * 4 + k) * 1024u));
  } else {
    // B(0): meta(0) -> corners(0) -> blend -> write buf0
    {
      int ci = (b * 9 + 0) * NSP + ps;
      mwv = W4[ci];
      mc4 = C4v[ci];
    }
    {
      unsigned p00 = mc4 & 0xffffu, p11 = mc4 >> 16;
      unsigned p01 = (p00 & ~63u) | (p11 & 63u);
      unsigned p10 = (p11 & ~63u) | (p00 & 63u);
      const unsigned short* base = xb + chb;   // c0(step0)=0
      const unsigned short* q00 = base + (p00 << 8);
      const unsigned short* q01 = base + (p01 << 8);
      const unsigned short* q10 = base + (p10 << 8);
      const unsigned short* q11 = base + (p11 << 8);
#pragma unroll
      for (int q = 0; q < 4; ++q) {
        c00[q] = *(const u32x4*)(q00 + q * 8);
        c01[q] = *(const u32x4*)(q01 + q * 8);
        c10[q] = *(const u32x4*)(q10 + q * 8);
        c11[q] = *(const u32x4*)(q11 + q * 8);
      }
#pragma unroll
      for (int q = 0; q < 4; ++q) {
        u32x4 o;
#pragma unroll
        for (int d = 0; d < 4; ++d) {
          float a0 = mwv[0] * bflo(c00[q][d]) + mwv[1] * bflo(c01[q][d]) +
                     mwv[2] * bflo(c10[q][d]) + mwv[3] * bflo(c11[q][d]);
          float a1 = mwv[0] * bfhi(c00[q][d]) + mwv[1] * bfhi(c01[q][d]) +
                     mwv[2] * bfhi(c10[q][d]) + mwv[3] * bfhi(c11[q][d]);
          o[d] = packbf2(a0, a1);
        }
        *(u32x4*)(ldsBbase + (unsigned)px * 128u +
                  (((unsigned)(chb * 2 + q * 16)) ^ swb)) = o;
      }
    }
    // meta(1) for step 0's corner-issue/blend
    {
      int ci = (b * 9 + 0) * NSP + ps;   // step1: k = 1>>2 = 0
      mwv = W4[ci];
      mc4 = C4v[ci];
    }
  }

  for (int t = 0; t < 36; ++t) {
    __syncthreads();  // full drain: DMA A(t) landed, B(t) published, all reads retired

    if (!isProd) {
      // issue DMA A(t+1) into the other A buffer (its reads ended before this barrier)
      if (t + 1 < 36) {
        const unsigned short* g0 = AWL + (t + 1) * 16384 + (w * 4) * 512 + l * 8;
        unsigned char* ldsAn = ldsbase + ((t + 1) & 1) * 32768;
#pragma unroll
        for (int k = 0; k < 4; ++k)
          dma16(g0 + k * 512, (unsigned short*)(ldsAn + (unsigned)(w * 4 + k) * 1024u));
      }
      unsigned char* ldsA = ldsbase + (t & 1) * 32768;
      unsigned char* ldsB = ldsBbase + (t & 1) * 16384;
      __builtin_amdgcn_s_setprio(1);
#pragma unroll
      for (int H = 0; H < 2; ++H) {
        bf16x8 af[4], bfr[4];
        const unsigned co = (unsigned)(H * 64 + ((l >> 4) * 16));
#pragma unroll
        for (int i = 0; i < 4; ++i) {
          int row = wm + i * 16 + (l & 15);
          af[i] = *(const bf16x8*)(ldsA + (unsigned)row * 128u +
                                   (co ^ ((unsigned)(row & 7) << 4)));
        }
#pragma unroll
        for (int j = 0; j < 4; ++j) {
          int col = wn + j * 16 + (l & 15);
          bfr[j] = *(const bf16x8*)(ldsB + (unsigned)col * 128u +
                                    (co ^ ((unsigned)(col & 7) << 4)));
        }
#pragma unroll
        for (int i = 0; i < 4; ++i)
#pragma unroll
          for (int j = 0; j < 4; ++j)
            acc[i][j] = __builtin_amdgcn_mfma_f32_16x16x32_bf16(af[i], bfr[j],
                                                                acc[i][j], 0, 0, 0);
      }
      __builtin_amdgcn_s_setprio(0);
    } else {
      // producer step t: corners(t+1) -> blend -> write B(t+1)
      f32x4 wvS = mwv;
      if (t + 1 < 36) {
        unsigned p00 = mc4 & 0xffffu, p11 = mc4 >> 16;
        unsigned p01 = (p00 & ~63u) | (p11 & 63u);
        unsigned p10 = (p11 & ~63u) | (p00 & 63u);
        const unsigned short* base = xb + (((t + 1) & 3) << 6) + chb;
        const unsigned short* q00 = base + (p00 << 8);
        const unsigned short* q01 = base + (p01 << 8);
        const unsigned short* q10 = base + (p10 << 8);
        const unsigned short* q11 = base + (p11 << 8);
#pragma unroll
        for (int q = 0; q < 4; ++q) {
          c00[q] = *(const u32x4*)(q00 + q * 8);
          c01[q] = *(const u32x4*)(q01 + q * 8);
          c10[q] = *(const u32x4*)(q10 + q * 8);
          c11[q] = *(const u32x4*)(q11 + q * 8);
        }
      }
      // load meta(t+2) (overwrites mc4/mwv; wvS holds step-(t+1) weights)
      if (t + 2 < 36) {
        int ci = (b * 9 + ((t + 2) >> 2)) * NSP + ps;
        mwv = W4[ci];
        mc4 = C4v[ci];
      }
      if (t + 1 < 36) {
        unsigned char* ldsBn = ldsBbase + ((t + 1) & 1) * 16384;
#pragma unroll
        for (int q = 0; q < 4; ++q) {
          u32x4 o;
#pragma unroll
          for (int d = 0; d < 4; ++d) {
            float a0 = wvS[0] * bflo(c00[q][d]) + wvS[1] * bflo(c01[q][d]) +
                       wvS[2] * bflo(c10[q][d]) + wvS[3] * bflo(c11[q][d]);
            float a1 = wvS[0] * bfhi(c00[q][d]) + wvS[1] * bfhi(c01[q][d]) +
                       wvS[2] * bfhi(c10[q][d]) + wvS[3] * bfhi(c11[q][d]);
            o[d] = packbf2(a0, a1);
          }
          *(u32x4*)(ldsBn + (unsigned)px * 128u +
                    (((unsigned)(chb * 2 + q * 16)) ^ swb)) = o;
        }
      }
    }
  }

  // epilogue (consumers): D layout col=lane&15, row=(lane>>4)*4+reg (m89)
  if (!isProd) {
    const int cn2 = l & 15;
    const int r0 = (l >> 4) * 4;
#pragma unroll
    for (int i = 0; i < 4; ++i) {
#pragma unroll
      for (int j = 0; j < 4; ++j) {
        int sc = s0 + wn + j * 16 + cn2;
#pragma unroll
        for (int r = 0; r < 4; ++r) {
          int o = wm + i * 16 + r0 + r;
          out[((b * 256 + o) << 12) + sc] = acc[i][j][r];
        }
      }
    }
  }
}

extern "C" void kernel_launch(void* const* d_in, const int* in_sizes, int n_in,
                              void* d_out, int out_size, void* d_ws, size_t ws_size,
                              hipStream_t stream) {
  const float* x = (const float*)d_in[0];
  const float* wof = (const float*)d_in[1];
  const float* wc = (const float*)d_in[2];
  float* out = (float*)d_out;
  char* ws = (char*)d_ws;

  // ws layout (total 24.2 MB)
  unsigned short* XH = (unsigned short*)(ws);              // 16,777,216 B
  unsigned short* AWL = (unsigned short*)(ws + 16777216);  //  1,179,648 B
  unsigned short* AF = (unsigned short*)(ws + 17956864);   //    294,912 B
  f32x4* W4 = (f32x4*)(ws + 18251776);                     //  4,718,592 B
  unsigned* C4 = (unsigned*)(ws + 22970368);               //  1,179,648 B (end 24,150,016)

  k_nhwc<<<512, 256, 0, stream>>>(x, XH);
  k_wprep_all<<<2880, 256, 0, stream>>>(wc, wof, AWL, AF);
  k_offc2<<<512, 256, 0, stream>>>(AF, XH, W4, C4);
  k_gemm<<<256, 768, 0, stream>>>(AWL, XH, W4, C4, out);
}

// Round 21
// 114.230 us; speedup vs baseline: 3.5666x; 1.2277x over previous
//
#include <hip/hip_runtime.h>
#include <hip/hip_bf16.h>

typedef float f32x4 __attribute__((ext_vector_type(4)));
typedef unsigned int u32x4 __attribute__((ext_vector_type(4)));
typedef __bf16 bf16x8 __attribute__((ext_vector_type(8)));

#define NSP 4096
#define KTOT 2304

static __device__ __forceinline__ float bflo(unsigned u) {
  return __builtin_bit_cast(float, u << 16);
}
static __device__ __forceinline__ float bfhi(unsigned u) {
  return __builtin_bit_cast(float, u & 0xffff0000u);
}
static __device__ __forceinline__ unsigned short bfbits(float f) {
  return __builtin_bit_cast(unsigned short, (__bf16)f);
}
static __device__ __forceinline__ unsigned packbf2(float f0, float f1) {
  return (unsigned)bfbits(f0) | ((unsigned)bfbits(f1) << 16);
}
static __device__ __forceinline__ float bf16f(unsigned short h) {
  return __builtin_bit_cast(float, (unsigned)h << 16);
}

// async global->LDS DMA, 16B per lane (lds dest = wave-uniform base + lane*16)
static __device__ __forceinline__ void dma16(const unsigned short* g, unsigned short* l) {
  __builtin_amdgcn_global_load_lds(
      (const __attribute__((address_space(1))) unsigned int*)g,
      (__attribute__((address_space(3))) unsigned int*)l, 16, 0, 0);
}

// ---------- x (B,C,H,W) f32 -> XH (B,H,W,C) bf16 ----------
__global__ __launch_bounds__(256) void k_nhwc(const float* __restrict__ x,
                                              unsigned short* __restrict__ XH) {
  const int by = blockIdx.x;            // b*64 + y
  const int t = threadIdx.x;
  const int xw = t & 63;
  const int cq = t >> 6;                // 0..3
  const float* xp = x + (((by >> 6) * 256 * 64 + (by & 63)) * 64 + xw);
  unsigned short* oh = XH + (by * 64 + xw) * 256;
#pragma unroll
  for (int j8 = 0; j8 < 8; ++j8) {
    const int c0 = cq * 64 + j8 * 8;
    u32x4 vh;
#pragma unroll
    for (int d = 0; d < 4; ++d) {
      float f0 = xp[(c0 + 2 * d) * 4096];
      float f1 = xp[(c0 + 2 * d + 1) * 4096];
      vh[d] = packbf2(f0, f1);
    }
    *(u32x4*)(oh + c0) = vh;
  }
}

// ---------- weight prep (AWL pre-inverse-swizzled for DMA; AF fragment-order) ----------
__global__ void k_wprep_all(const float* __restrict__ wc, const float* __restrict__ wof,
                            unsigned short* __restrict__ AWL,
                            unsigned short* __restrict__ AF) {
  int idx = blockIdx.x * 256 + threadIdx.x;
  if (idx < 589824) {                     // 36*16384
    int ks = idx / 16384;
    int e = idx - ks * 16384;
    int row = e >> 6;                     // output channel o (0..255)
    int se = e & 63;                      // element within 128B LDS row
    int offb = (se * 2) ^ ((row & 7) << 4);  // unswizzled byte offset
    int col = ks * 64 + (offb >> 1);      // global K index
    int c = col & 255, tap = col >> 8;
    AWL[idx] = bfbits(wc[(row * 256 + c) * 9 + tap]);
  } else {
    int j = idx - 589824;
    if (j < 147456) {                     // 72*2048
      int skc = j >> 11;
      int r = j & 2047;
      int fi = r >> 9;                    // 0:hi m, 1:hi m+16, 2:lo m, 3:lo m+16
      int lane = (r >> 3) & 63;
      int e = r & 7;
      int ks = skc >> 1, kc = skc & 1;
      int tap = ks >> 2, q = ks & 3;
      int mr = lane & 15, ko = (lane >> 4) * 8;
      int m = (fi & 1) * 16 + mr;
      int gcol = tap * 256 + q * 64 + ko + kc * 32 + e;
      int c = gcol & 255;
      int t = gcol >> 8;
      float v = (m < 27) ? wof[(m * 256 + c) * 9 + t] : 0.f;
      unsigned short h = bfbits(v);
      AF[j] = (fi >> 1) ? bfbits(v - bf16f(h)) : h;
    }
  }
}

// ---------- offset conv: LDS-staged GEMM, dbuf + prefetch, coalesced A ----------
__global__ __launch_bounds__(256) void k_offc2(const unsigned short* __restrict__ AF,
                                               const unsigned short* __restrict__ XH,
                                               f32x4* __restrict__ W4,
                                               unsigned* __restrict__ C4) {
  __shared__ u32x4 ldsq[1024];   // 16 KB: 2 x 8 KB B-tile dbuf; reused for 8 KB acc
  unsigned char* ldsbase = (unsigned char*)ldsq;
  float* lds32 = (float*)ldsq;

  const int tid = threadIdx.x;
  const int bid = blockIdx.x;            // y(64) x b(8)
  const int b = bid & 7;                 // XCD swizzle: one batch per XCD
  const int y = bid >> 3;
  const int l = tid & 63;
  const int w = tid >> 6;

  const unsigned short* xb = XH + b * (64 * 64 * 256);
  const int sp = tid >> 2;
  const int qtr = tid & 3;
  const unsigned swb = (unsigned)(sp & 7) << 4;
  const int col = w * 16 + (l & 15);
  const unsigned swc = (unsigned)(col & 7) << 4;

  f32x4 acc0 = (f32x4){0.f, 0.f, 0.f, 0.f};
  f32x4 acc1 = (f32x4){0.f, 0.f, 0.f, 0.f};
  u32x4 v0, v1;

  // prologue: stage step 0 into buffer 0
  {
    const int yy = y - 1;
    const int xx = sp - 1;
    const bool valid = ((unsigned)yy < 64u) & ((unsigned)xx < 64u);
    const int yyc = min(max(yy, 0), 63), xxc = min(max(xx, 0), 63);
    const unsigned short* src = xb + ((yyc * 64 + xxc) * 256 + qtr * 16);
    u32x4 z = (u32x4){0u, 0u, 0u, 0u};
    v0 = valid ? *(const u32x4*)src : z;
    v1 = valid ? *(const u32x4*)(src + 8) : z;
    *(u32x4*)(ldsbase + (unsigned)sp * 128u + (((unsigned)(qtr * 32)) ^ swb)) = v0;
    *(u32x4*)(ldsbase + (unsigned)sp * 128u + (((unsigned)(qtr * 32 + 16)) ^ swb)) = v1;
  }

  for (int ks = 0; ks < 36; ++ks) {
    unsigned char* ldsB = ldsbase + (ks & 1) * 8192;
    unsigned char* ldsBn = ldsbase + ((ks & 1) ^ 1) * 8192;
    const bool pf = (ks + 1 < 36);

    // prefetch next stage BEFORE the barrier (stays in flight across it)
    if (pf) {
      int tap = (ks + 1) >> 2, q = (ks + 1) & 3;
      int yy = y + tap / 3 - 1, xx = sp + tap % 3 - 1;
      bool valid = ((unsigned)yy < 64u) & ((unsigned)xx < 64u);
      int yyc = min(max(yy, 0), 63), xxc = min(max(xx, 0), 63);
      const unsigned short* src = xb + ((yyc * 64 + xxc) * 256 + q * 64 + qtr * 16);
      u32x4 z = (u32x4){0u, 0u, 0u, 0u};
      v0 = valid ? *(const u32x4*)src : z;
      v1 = valid ? *(const u32x4*)(src + 8) : z;
    }

    // LDS-only barrier: publish buf[cur] writes, retire buf[cur^1] reads
    asm volatile("s_waitcnt lgkmcnt(0)" ::: "memory");
    __builtin_amdgcn_s_barrier();

    const unsigned short* af = AF + ks * 4096;
#pragma unroll
    for (int kc = 0; kc < 2; ++kc) {
      bf16x8 ah0 = *(const bf16x8*)(af + kc * 2048 + l * 8);
      bf16x8 ah1 = *(const bf16x8*)(af + kc * 2048 + 512 + l * 8);
      bf16x8 al0 = *(const bf16x8*)(af + kc * 2048 + 1024 + l * 8);
      bf16x8 al1 = *(const bf16x8*)(af + kc * 2048 + 1536 + l * 8);
      bf16x8 bh = *(const bf16x8*)(ldsB + (unsigned)col * 128u +
                                   (((unsigned)(kc * 64 + (l >> 4) * 16)) ^ swc));
      acc0 = __builtin_amdgcn_mfma_f32_16x16x32_bf16(ah0, bh, acc0, 0, 0, 0);
      acc1 = __builtin_amdgcn_mfma_f32_16x16x32_bf16(ah1, bh, acc1, 0, 0, 0);
      acc0 = __builtin_amdgcn_mfma_f32_16x16x32_bf16(al0, bh, acc0, 0, 0, 0);
      acc1 = __builtin_amdgcn_mfma_f32_16x16x32_bf16(al1, bh, acc1, 0, 0, 0);
    }

    // write next stage into the other buffer (read side untouched)
    if (pf) {
      *(u32x4*)(ldsBn + (unsigned)sp * 128u + (((unsigned)(qtr * 32)) ^ swb)) = v0;
      *(u32x4*)(ldsBn + (unsigned)sp * 128u + (((unsigned)(qtr * 32 + 16)) ^ swb)) = v1;
    }
  }

  // stage acc -> lds32 [32 m][64 px]  (D layout: col=lane&15, row=(l>>4)*4+reg)
  __syncthreads();
#pragma unroll
  for (int mf = 0; mf < 2; ++mf) {
    f32x4 a = mf ? acc1 : acc0;
#pragma unroll
    for (int r = 0; r < 4; ++r) {
      int m = mf * 16 + (l >> 4) * 4 + r;
      int px = w * 16 + (l & 15);
      lds32[m * 64 + px] = a[r];
    }
  }
  __syncthreads();

  // fused xform: per (k, px) compute bilinear weights + packed corner indices
#pragma unroll
  for (int it = 0; it < 3; ++it) {
    int idx = tid + it * 256;
    if (idx < 9 * 64) {
      int k = idx >> 6, px = idx & 63;
      float oy = lds32[k * 64 + px];
      float ox = lds32[(9 + k) * 64 + px];
      float lg = lds32[(18 + k) * 64 + px];
      int s = y * 64 + px;
      float py = oy + (float)y - 1.f + (float)(k / 3);
      float pxf = ox + (float)px - 1.f + (float)(k % 3);
      float mk = 1.f / (1.f + __expf(-lg));

      float y0f = floorf(py), x0f = floorf(pxf);
      float ly = py - y0f, lx = pxf - x0f;
      int y0 = (int)y0f, x0 = (int)x0f;
      int y1 = y0 + 1, x1 = x0 + 1;
      float omy = 1.f - ly, omx = 1.f - lx;
      bool y0v = (unsigned)y0 < 64u, y1v = (unsigned)y1 < 64u;
      bool x0v = (unsigned)x0 < 64u, x1v = (unsigned)x1 < 64u;
      f32x4 wv;
      wv[0] = (y0v && x0v) ? omy * omx * mk : 0.f;
      wv[1] = (y0v && x1v) ? omy * lx * mk : 0.f;
      wv[2] = (y1v && x0v) ? ly * omx * mk : 0.f;
      wv[3] = (y1v && x1v) ? ly * lx * mk : 0.f;
      int y0c = min(max(y0, 0), 63), y1c = min(max(y1, 0), 63);
      int x0c = min(max(x0, 0), 63), x1c = min(max(x1, 0), 63);
      unsigned p00 = (unsigned)(y0c * 64 + x0c);
      unsigned p11 = (unsigned)(y1c * 64 + x1c);
      int ci = (b * 9 + k) * NSP + s;
      W4[ci] = wv;
      C4[ci] = p00 | (p11 << 16);
    }
  }
}

// ---------- fused sampling + implicit GEMM (A DMA + counted-vmcnt barrier) ----------
struct Bld16 {
  u32x4 g00a, g00b, g01a, g01b, g10a, g10b, g11a, g11b;
  f32x4 wv;
};

static __device__ __forceinline__ void loadMeta(const f32x4* __restrict__ W4,
                                                const unsigned* __restrict__ C4,
                                                int b, int k, int s,
                                                f32x4& wv, unsigned& c4) {
  int ci = (b * 9 + k) * NSP + s;
  wv = W4[ci];
  c4 = C4[ci];
}

static __device__ __forceinline__ void loadCorners(const unsigned short* __restrict__ xb,
                                                   f32x4 wv, unsigned c4, int c0, int bc,
                                                   Bld16& r) {
  r.wv = wv;
  unsigned p00 = c4 & 0xffffu, p11 = c4 >> 16;
  unsigned p01 = (p00 & ~63u) | (p11 & 63u);
  unsigned p10 = (p11 & ~63u) | (p00 & 63u);
  const unsigned short* base = xb + (c0 + bc);
  const unsigned short* q00 = base + (p00 << 8);
  const unsigned short* q01 = base + (p01 << 8);
  const unsigned short* q10 = base + (p10 << 8);
  const unsigned short* q11 = base + (p11 << 8);
  r.g00a = *(const u32x4*)q00;
  r.g00b = *(const u32x4*)(q00 + 8);
  r.g01a = *(const u32x4*)q01;
  r.g01b = *(const u32x4*)(q01 + 8);
  r.g10a = *(const u32x4*)q10;
  r.g10b = *(const u32x4*)(q10 + 8);
  r.g11a = *(const u32x4*)q11;
  r.g11b = *(const u32x4*)(q11 + 8);
}

static __device__ __forceinline__ void blendB16(const Bld16& r, u32x4& o0, u32x4& o1) {
#pragma unroll
  for (int d = 0; d < 4; ++d) {
    float a0 = r.wv[0] * bflo(r.g00a[d]) + r.wv[1] * bflo(r.g01a[d]) +
               r.wv[2] * bflo(r.g10a[d]) + r.wv[3] * bflo(r.g11a[d]);
    float a1 = r.wv[0] * bfhi(r.g00a[d]) + r.wv[1] * bfhi(r.g01a[d]) +
               r.wv[2] * bfhi(r.g10a[d]) + r.wv[3] * bfhi(r.g11a[d]);
    o0[d] = packbf2(a0, a1);
    float b0 = r.wv[0] * bflo(r.g00b[d]) + r.wv[1] * bflo(r.g01b[d]) +
               r.wv[2] * bflo(r.g10b[d]) + r.wv[3] * bflo(r.g11b[d]);
    float b1 = r.wv[0] * bfhi(r.g00b[d]) + r.wv[1] * bfhi(r.g01b[d]) +
               r.wv[2] * bfhi(r.g10b[d]) + r.wv[3] * bfhi(r.g11b[d]);
    o1[d] = packbf2(b0, b1);
  }
}

__global__ __launch_bounds__(512) void k_gemm(const unsigned short* __restrict__ AWL,
                                              const unsigned short* __restrict__ XH,
                                              const f32x4* __restrict__ W4,
                                              const unsigned* __restrict__ C4v,
                                              float* __restrict__ out) {
  // double buffer: per buffer 48 KB = A [256][64 bf16] (32 KB, DMA) + B [128][64 bf16] (16 KB)
  __shared__ u32x4 lds2[2][3072];
  unsigned char* ldsbase = (unsigned char*)lds2;

  const int tid = threadIdx.x;
  const int bid = blockIdx.x;
  const int b = bid & 7;          // XCD swizzle: one batch per XCD
  const int s0 = (bid >> 3) * 128;

  const int l = tid & 63;
  const int w = tid >> 6;
  const int wm = (w >> 1) * 64;  // 4 M-waves
  const int wn = (w & 1) * 64;   // 2 N-waves

  const int bn = tid >> 2;
  const int bc = (tid & 3) * 16;
  const int s = s0 + bn;
  const unsigned swb = (unsigned)(bn & 7) << 4;
  const unsigned short* xb = XH + b * (64 * 64 * 256);

  f32x4 acc[4][4];
#pragma unroll
  for (int i = 0; i < 4; ++i)
#pragma unroll
    for (int j = 0; j < 4; ++j) acc[i][j] = (f32x4){0.f, 0.f, 0.f, 0.f};

  // 2-deep pipeline register sets (named, statically indexed — rule #20)
  f32x4 mwvA, mwvB;
  unsigned mc4A, mc4B;
  Bld16 bldA, bldB;

  // ---- prologue ----
  loadMeta(W4, C4v, b, 0, s, mwvA, mc4A);   // meta(0)
  loadMeta(W4, C4v, b, 0, s, mwvB, mc4B);   // meta(1)
  {
    // DMA A(0) into buffer 0 (linear deposit; AWL is pre-inverse-swizzled)
    const unsigned short* g0 = AWL + (w * 4) * 512 + l * 8;
#pragma unroll
    for (int k = 0; k < 4; ++k)
      dma16(g0 + k * 512, (unsigned short*)(ldsbase + (unsigned)(w * 4 + k) * 1024u));
  }
  loadCorners(xb, mwvA, mc4A, 0, bc, bldA);              // corners(0)
  loadMeta(W4, C4v, b, 0, s, mwvA, mc4A);   // meta(2)
  {
    u32x4 o0, o1;
    blendB16(bldA, o0, o1);
    unsigned char* ldsB = ldsbase + 32768;
    const unsigned bbase = (unsigned)bn * 128u;
    *(u32x4*)(ldsB + bbase + (((unsigned)(bc * 2)) ^ swb)) = o0;
    *(u32x4*)(ldsB + bbase + (((unsigned)(bc * 2 + 16)) ^ swb)) = o1;
  }
  loadCorners(xb, mwvB, mc4B, 64, bc, bldB);             // corners(1)

  auto mfma_half = [&](unsigned char* ldsA, unsigned char* ldsB, int H) {
    bf16x8 af[4], bfr[4];
    const unsigned co = (unsigned)(H * 64 + ((l >> 4) * 16));
#pragma unroll
    for (int i = 0; i < 4; ++i) {
      int row = wm + i * 16 + (l & 15);
      af[i] = *(const bf16x8*)(ldsA + (unsigned)row * 128u +
                               (co ^ ((unsigned)(row & 7) << 4)));
    }
#pragma unroll
    for (int j = 0; j < 4; ++j) {
      int col = wn + j * 16 + (l & 15);
      bfr[j] = *(const bf16x8*)(ldsB + (unsigned)col * 128u +
                                (co ^ ((unsigned)(col & 7) << 4)));
    }
#pragma unroll
    for (int i = 0; i < 4; ++i)
#pragma unroll
      for (int j = 0; j < 4; ++j)
        acc[i][j] = __builtin_amdgcn_mfma_f32_16x16x32_bf16(af[i], bfr[j],
                                                            acc[i][j], 0, 0, 0);
  };

  // step KS. Barrier uses COUNTED vmcnt (T4): retire exactly DMA A(KS) — the 4
  // oldest VMEM ops — while corners(KS+1)+meta(KS+2) (10 ops) stay in flight.
  // Queue at barrier top of step KS (verified): DMA(KS)x4, corners(KS+1)x8,
  // meta(KS+2)x2  ->  nw = 10 for KS<=33; KS=34: meta(36) absent -> nw = 8;
  // KS=35: nothing newer than DMA -> nw = 0.
  auto gstep = [&](int KS, int nw, Bld16& bldI, f32x4& mwvI, unsigned& mc4I,
                   f32x4& mwvO, unsigned& mc4O, Bld16& bldU) {
    const int cur = KS & 1;
    unsigned char* ldsA = ldsbase + cur * 49152;
    unsigned char* ldsB = ldsA + 32768;
    unsigned char* ldsAn = ldsbase + (cur ^ 1) * 49152;
    unsigned char* ldsBn = ldsAn + 32768;

    if (nw == 10) {
      asm volatile("s_waitcnt vmcnt(10) lgkmcnt(0)" ::: "memory");
    } else if (nw == 8) {
      asm volatile("s_waitcnt vmcnt(8) lgkmcnt(0)" ::: "memory");
    } else {
      asm volatile("s_waitcnt vmcnt(0) lgkmcnt(0)" ::: "memory");
    }
    __builtin_amdgcn_s_barrier();

    // issue DMA A(KS+1) — targets buf[cur^1], whose reads this barrier just retired
    if (KS + 1 < 36) {
      const unsigned short* g0 = AWL + (KS + 1) * 16384 + (w * 4) * 512 + l * 8;
#pragma unroll
      for (int k = 0; k < 4; ++k)
        dma16(g0 + k * 512, (unsigned short*)(ldsAn + (unsigned)(w * 4 + k) * 1024u));
    }

    __builtin_amdgcn_s_setprio(1);
    mfma_half(ldsA, ldsB, 0);
    __builtin_amdgcn_s_setprio(0);

    // issue corners(KS+2) — addresses from meta loaded a full step ago
    if (KS + 2 < 36)
      loadCorners(xb, mwvI, mc4I, ((KS + 2) & 3) << 6, bc, bldI);
    // issue meta(KS+3) into the freed opposite meta set
    if (KS + 3 < 36)
      loadMeta(W4, C4v, b, (KS + 3) >> 2, s, mwvO, mc4O);

    __builtin_amdgcn_s_setprio(1);
    mfma_half(ldsA, ldsB, 1);
    __builtin_amdgcn_s_setprio(0);

    // blend + stage B(KS+1) into the other buffer (loads have flown ~1.5 steps,
    // now UNBROKEN by the barrier drain)
    if (KS + 1 < 36) {
      u32x4 o0, o1;
      blendB16(bldU, o0, o1);
      const unsigned bbase = (unsigned)bn * 128u;
      *(u32x4*)(ldsBn + bbase + (((unsigned)(bc * 2)) ^ swb)) = o0;
      *(u32x4*)(ldsBn + bbase + (((unsigned)(bc * 2 + 16)) ^ swb)) = o1;
    }
  };

  for (int ks2 = 0; ks2 < 34; ks2 += 2) {
    gstep(ks2, 10, bldA, mwvA, mc4A, mwvB, mc4B, bldB);
    gstep(ks2 + 1, 10, bldB, mwvB, mc4B, mwvA, mc4A, bldA);
  }
  gstep(34, 8, bldA, mwvA, mc4A, mwvB, mc4B, bldB);
  gstep(35, 0, bldB, mwvB, mc4B, mwvA, mc4A, bldA);

  // epilogue: D layout col=lane&15, row=(lane>>4)*4+reg (m89)
  const int cn2 = l & 15;
  const int r0 = (l >> 4) * 4;
#pragma unroll
  for (int i = 0; i < 4; ++i) {
#pragma unroll
    for (int j = 0; j < 4; ++j) {
      int sc = s0 + wn + j * 16 + cn2;
#pragma unroll
      for (int r = 0; r < 4; ++r) {
        int o = wm + i * 16 + r0 + r;
        out[((b * 256 + o) << 12) + sc] = acc[i][j][r];
      }
    }
  }
}

extern "C" void kernel_launch(void* const* d_in, const int* in_sizes, int n_in,
                              void* d_out, int out_size, void* d_ws, size_t ws_size,
                              hipStream_t stream) {
  const float* x = (const float*)d_in[0];
  const float* wof = (const float*)d_in[1];
  const float* wc = (const float*)d_in[2];
  float* out = (float*)d_out;
  char* ws = (char*)d_ws;

  // ws layout (total 24.2 MB)
  unsigned short* XH = (unsigned short*)(ws);              // 16,777,216 B
  unsigned short* AWL = (unsigned short*)(ws + 16777216);  //  1,179,648 B
  unsigned short* AF = (unsigned short*)(ws + 17956864);   //    294,912 B
  f32x4* W4 = (f32x4*)(ws + 18251776);                     //  4,718,592 B
  unsigned* C4 = (unsigned*)(ws + 22970368);               //  1,179,648 B (end 24,150,016)

  k_nhwc<<<512, 256, 0, stream>>>(x, XH);
  k_wprep_all<<<2880, 256, 0, stream>>>(wc, wof, AWL, AF);
  k_offc2<<<512, 256, 0, stream>>>(AF, XH, W4, C4);
  k_gemm<<<256, 512, 0, stream>>>(AWL, XH, W4, C4, out);
}